// Round 1
// baseline (6875.780 us; speedup 1.0000x reference)
//
#include <hip/hip_runtime.h>
#include <math.h>

#define NB 8
#define NL 512
#define NS 128
#define ND 256

constexpr float SHARPNESS = 2.0f;
constexpr float WTGT = 1.0f / 2000.0f;
constexpr float EPS = 1e-12f;

// ---------------------------------------------------------------------------
// Projection kernel: Q = h Wq^T + bq, K, V, gate = sigmoid(h Wg^T + bg)
// grid = (NB*NL)/16 blocks, 256 threads. Each block: 16 (b,l) rows, thread = d.
// ---------------------------------------------------------------------------
__global__ __launch_bounds__(256) void proj_kernel(
    const float* __restrict__ hseq,
    const float* __restrict__ Wq, const float* __restrict__ bq,
    const float* __restrict__ Wk, const float* __restrict__ bk,
    const float* __restrict__ Wv, const float* __restrict__ bv,
    const float* __restrict__ Wg, const float* __restrict__ bg,
    float* __restrict__ Qo, float* __restrict__ Ko,
    float* __restrict__ Vo, float* __restrict__ Go)
{
    __shared__ float hs[16][ND + 4];   // padded rows, 16B-aligned (260*4=1040)
    const int tid = threadIdx.x;
    const int bl0 = blockIdx.x * 16;

    for (int k = 0; k < 16; ++k)
        hs[k][tid] = hseq[(size_t)(bl0 + k) * ND + tid];
    __syncthreads();

    const int d = tid;
    for (int mat = 0; mat < 3; ++mat) {
        const float* W    = (mat == 0) ? Wq : (mat == 1) ? Wk : Wv;
        const float* bias = (mat == 0) ? bq : (mat == 1) ? bk : bv;
        float* O          = (mat == 0) ? Qo : (mat == 1) ? Ko : Vo;
        float acc[16];
        const float b0 = bias[d];
        #pragma unroll
        for (int i = 0; i < 16; ++i) acc[i] = b0;
        const float4* Wrow = (const float4*)(W + (size_t)d * ND);
        for (int j4 = 0; j4 < 64; ++j4) {
            const float4 w4 = Wrow[j4];
            #pragma unroll
            for (int i = 0; i < 16; ++i) {
                const float4 h4 = *(const float4*)&hs[i][j4 * 4];
                acc[i] = fmaf(w4.x, h4.x,
                         fmaf(w4.y, h4.y,
                         fmaf(w4.z, h4.z,
                         fmaf(w4.w, h4.w, acc[i]))));
            }
        }
        #pragma unroll
        for (int i = 0; i < 16; ++i)
            O[(size_t)(bl0 + i) * ND + d] = acc[i];
    }

    // gate: row i = tid>>4, j-chunk = (tid&15)*16, 16-lane shuffle reduce
    {
        const int i = tid >> 4, j0 = (tid & 15) * 16;
        float p = 0.f;
        #pragma unroll
        for (int j = 0; j < 16; ++j)
            p = fmaf(Wg[j0 + j], hs[i][j0 + j], p);
        #pragma unroll
        for (int m = 1; m < 16; m <<= 1) p += __shfl_xor(p, m);
        if ((tid & 15) == 0) {
            const float z = p + bg[0];
            Go[bl0 + i] = 1.f / (1.f + __expf(-z));
        }
    }
}

// ---------------------------------------------------------------------------
// Per-(b,l) squared norms of q and k. grid = NB*NL blocks, 64 threads (1 wave).
// ---------------------------------------------------------------------------
__global__ __launch_bounds__(64) void norm_kernel(
    const float* __restrict__ Qb, const float* __restrict__ Kb,
    float* __restrict__ Qn2, float* __restrict__ Kn2)
{
    const int bl = blockIdx.x;
    const int lane = threadIdx.x;
    const float4 q4 = ((const float4*)(Qb + (size_t)bl * ND))[lane];
    const float4 k4 = ((const float4*)(Kb + (size_t)bl * ND))[lane];
    float qq = q4.x*q4.x + q4.y*q4.y + q4.z*q4.z + q4.w*q4.w;
    float kk = k4.x*k4.x + k4.y*k4.y + k4.z*k4.z + k4.w*k4.w;
    #pragma unroll
    for (int m = 1; m < 64; m <<= 1) { qq += __shfl_xor(qq, m); kk += __shfl_xor(kk, m); }
    if (lane == 0) { Qn2[bl] = qq; Kn2[bl] = kk; }
}

// ---------------------------------------------------------------------------
// sp = mean_l (mean_b gate - WTGT)^2. 1 block, 256 threads.
// ---------------------------------------------------------------------------
__global__ __launch_bounds__(256) void sp_kernel(
    const float* __restrict__ Go, float* __restrict__ out_sp)
{
    const int tid = threadIdx.x;
    float s = 0.f;
    for (int l = tid; l < NL; l += 256) {
        float gsum = 0.f;
        #pragma unroll
        for (int b = 0; b < NB; ++b) gsum += Go[b * NL + l];
        const float d = gsum * (1.f / NB) - WTGT;
        s += d * d;
    }
    #pragma unroll
    for (int m = 1; m < 64; m <<= 1) s += __shfl_xor(s, m);
    __shared__ float ws[4];
    if ((tid & 63) == 0) ws[tid >> 6] = s;
    __syncthreads();
    if (tid == 0) out_sp[0] = (ws[0] + ws[1] + ws[2] + ws[3]) * (1.f / NL);
}

// ---------------------------------------------------------------------------
// Sequential scan. grid = NB blocks, 512 threads (8 waves).
// Thread t: row r = t>>2 (0..127), chunk c = t&3, owns mem[r][c*64 .. c*64+63]
// entirely in registers. 3 barriers/step.
// ---------------------------------------------------------------------------
__global__ __launch_bounds__(512, 2) void scan_kernel(
    const float* __restrict__ init_mem, const float* __restrict__ masks,
    const float* __restrict__ Qb, const float* __restrict__ Kb,
    const float* __restrict__ Vb, const float* __restrict__ Gb,
    const float* __restrict__ Qn2, const float* __restrict__ Kn2,
    float* __restrict__ out)
{
    const int b    = blockIdx.x;
    const int t    = (int)threadIdx.x;
    const int lane = t & 63;
    const int w    = t >> 6;
    const int r    = t >> 2;
    const int c    = t & 3;
    const int d0   = c * 64;

    __shared__ float redmax[2][8];
    __shared__ float redsum[2][8];
    __shared__ float rvpart[8][ND];

    float mem[64];
    {
        const float4* p4 = (const float4*)(init_mem + ((size_t)b * NS + r) * ND + d0);
        #pragma unroll
        for (int j4 = 0; j4 < 16; ++j4) {
            const float4 v = p4[j4];
            mem[4*j4+0] = v.x; mem[4*j4+1] = v.y; mem[4*j4+2] = v.z; mem[4*j4+3] = v.w;
        }
    }

    float qv[64], kv[64];
    {
        const float4* qp = (const float4*)(Qb + ((size_t)b * NL) * ND + d0);
        const float4* kp = (const float4*)(Kb + ((size_t)b * NL) * ND + d0);
        #pragma unroll
        for (int j4 = 0; j4 < 16; ++j4) {
            const float4 a_ = qp[j4];
            qv[4*j4+0] = a_.x; qv[4*j4+1] = a_.y; qv[4*j4+2] = a_.z; qv[4*j4+3] = a_.w;
            const float4 b_ = kp[j4];
            kv[4*j4+0] = b_.x; kv[4*j4+1] = b_.y; kv[4*j4+2] = b_.z; kv[4*j4+3] = b_.w;
        }
    }

    const bool h1 = (lane & 4)  != 0;
    const bool h2 = (lane & 8)  != 0;
    const bool h3 = (lane & 16) != 0;
    const bool h4 = (lane & 32) != 0;
    const int off = (h1 ? 32 : 0) + (h2 ? 16 : 0) + (h3 ? 8 : 0) + (h4 ? 4 : 0);

    for (int step = 0; step < NL; ++step) {
        const size_t blt = (size_t)b * NL + step;
        const float qn2  = Qn2[blt];
        const float kn2  = Kn2[blt];
        const float g    = Gb[blt];
        const float mval = masks[blt];

        // ---- pass 1: fused dots + row norm ----
        float dq = 0.f, dk = 0.f, nn = 0.f;
        #pragma unroll
        for (int j = 0; j < 64; ++j) {
            const float m_ = mem[j];
            dq = fmaf(m_, qv[j], dq);
            dk = fmaf(m_, kv[j], dk);
            nn = fmaf(m_, m_, nn);
        }

        // prefetch q,k for step+1 (last-step over-read lands inside K/V regions: safe)
        {
            const float4* qp = (const float4*)(Qb + (blt + 1) * ND + d0);
            const float4* kp = (const float4*)(Kb + (blt + 1) * ND + d0);
            #pragma unroll
            for (int j4 = 0; j4 < 16; ++j4) {
                const float4 a_ = qp[j4];
                qv[4*j4+0] = a_.x; qv[4*j4+1] = a_.y; qv[4*j4+2] = a_.z; qv[4*j4+3] = a_.w;
                const float4 b_ = kp[j4];
                kv[4*j4+0] = b_.x; kv[4*j4+1] = b_.y; kv[4*j4+2] = b_.z; kv[4*j4+3] = b_.w;
            }
        }

        // combine the 4 chunk-partials of this row
        dq += __shfl_xor(dq, 1); dq += __shfl_xor(dq, 2);
        dk += __shfl_xor(dk, 1); dk += __shfl_xor(dk, 2);
        nn += __shfl_xor(nn, 1); nn += __shfl_xor(nn, 2);

        const float rinv = 1.f / fmaxf(sqrtf(nn),  EPS);
        const float qni  = 1.f / fmaxf(sqrtf(qn2), EPS);
        const float kni  = 1.f / fmaxf(sqrtf(kn2), EPS);
        const float sim  = dq * rinv * qni * SHARPNESS;
        const float wsim = dk * rinv * kni * SHARPNESS;

        // ---- softmax over 128 rows (each row duplicated x4 in lanes) ----
        float mx1 = sim, mx2 = wsim;
        #pragma unroll
        for (int m_ = 1; m_ < 64; m_ <<= 1) {
            mx1 = fmaxf(mx1, __shfl_xor(mx1, m_));
            mx2 = fmaxf(mx2, __shfl_xor(mx2, m_));
        }
        if (lane == 0) { redmax[0][w] = mx1; redmax[1][w] = mx2; }
        __syncthreads();
        float M1 = redmax[0][0], M2 = redmax[1][0];
        #pragma unroll
        for (int i = 1; i < 8; ++i) {
            M1 = fmaxf(M1, redmax[0][i]);
            M2 = fmaxf(M2, redmax[1][i]);
        }
        const float e1 = __expf(sim  - M1);
        const float e2 = __expf(wsim - M2);
        float s1 = e1, s2 = e2;
        #pragma unroll
        for (int m_ = 1; m_ < 64; m_ <<= 1) {
            s1 += __shfl_xor(s1, m_);
            s2 += __shfl_xor(s2, m_);
        }
        if (lane == 0) { redsum[0][w] = s1; redsum[1][w] = s2; }
        __syncthreads();
        float S1 = 0.f, S2 = 0.f;
        #pragma unroll
        for (int i = 0; i < 8; ++i) { S1 += redsum[0][i]; S2 += redsum[1][i]; }
        const float rw = e1 * (4.f / S1);              // per-lane dup x4 compensated
        const float a  = g * (e2 * (4.f / S2));        // write coefficient for this row

        // ---- read_v: reduce-scatter over the 16 lanes {c, c+4, ..., c+60} ----
        float red[32];
        #pragma unroll
        for (int k2 = 0; k2 < 32; ++k2) {
            const float plo = rw * mem[k2];
            const float phi = rw * mem[32 + k2];
            red[k2] = (h1 ? phi : plo) + __shfl_xor(h1 ? plo : phi, 4);
        }
        #pragma unroll
        for (int k2 = 0; k2 < 16; ++k2)
            red[k2] = (h2 ? red[16+k2] : red[k2]) + __shfl_xor(h2 ? red[k2] : red[16+k2], 8);
        #pragma unroll
        for (int k2 = 0; k2 < 8; ++k2)
            red[k2] = (h3 ? red[8+k2] : red[k2]) + __shfl_xor(h3 ? red[k2] : red[8+k2], 16);
        #pragma unroll
        for (int k2 = 0; k2 < 4; ++k2)
            red[k2] = (h4 ? red[4+k2] : red[k2]) + __shfl_xor(h4 ? red[k2] : red[4+k2], 32);
        *(float4*)&rvpart[w][d0 + off] = make_float4(red[0], red[1], red[2], red[3]);

        // ---- update mem (v streamed from L2; 16-lane address dedup) ----
        {
            const float4* vp = (const float4*)(Vb + blt * ND + d0);
            #pragma unroll
            for (int j4 = 0; j4 < 16; ++j4) {
                const float4 v4 = vp[j4];
                mem[4*j4+0] = fmaf(a, v4.x - mem[4*j4+0], mem[4*j4+0]);
                mem[4*j4+1] = fmaf(a, v4.y - mem[4*j4+1], mem[4*j4+1]);
                mem[4*j4+2] = fmaf(a, v4.z - mem[4*j4+2], mem[4*j4+2]);
                mem[4*j4+3] = fmaf(a, v4.w - mem[4*j4+3], mem[4*j4+3]);
            }
        }
        if (mval != 1.0f) {            // uniform branch; masks are all-ones here
            #pragma unroll
            for (int j = 0; j < 64; ++j) mem[j] *= mval;
        }

        __syncthreads();
        if (t < ND) {
            float s = 0.f;
            #pragma unroll
            for (int ww2 = 0; ww2 < 8; ++ww2) s += rvpart[ww2][t];
            out[blt * ND + t] = s;
        }
        // no trailing barrier needed: next-iter rvpart write is behind 2 barriers
    }
}

// ---------------------------------------------------------------------------
extern "C" void kernel_launch(void* const* d_in, const int* in_sizes, int n_in,
                              void* d_out, int out_size, void* d_ws, size_t ws_size,
                              hipStream_t stream)
{
    (void)in_sizes; (void)n_in; (void)out_size; (void)ws_size;

    const float* init_mem = (const float*)d_in[0];
    const float* hseq     = (const float*)d_in[1];
    const float* masks    = (const float*)d_in[2];
    const float* Wq = (const float*)d_in[3];  const float* bq = (const float*)d_in[4];
    const float* Wk = (const float*)d_in[5];  const float* bk = (const float*)d_in[6];
    const float* Wv = (const float*)d_in[7];  const float* bv = (const float*)d_in[8];
    const float* Wg = (const float*)d_in[9];  const float* bg = (const float*)d_in[10];
    float* out = (float*)d_out;

    float* ws  = (float*)d_ws;
    float* Qb  = ws;                                   // NB*NL*ND
    float* Kb  = Qb + (size_t)NB * NL * ND;            // NB*NL*ND
    float* Vb  = Kb + (size_t)NB * NL * ND;            // NB*NL*ND
    float* Gb  = Vb + (size_t)NB * NL * ND;            // NB*NL
    float* Qn2 = Gb + NB * NL;                         // NB*NL
    float* Kn2 = Qn2 + NB * NL;                        // NB*NL

    proj_kernel<<<(NB * NL) / 16, 256, 0, stream>>>(hseq, Wq, bq, Wk, bk, Wv, bv,
                                                    Wg, bg, Qb, Kb, Vb, Gb);
    norm_kernel<<<NB * NL, 64, 0, stream>>>(Qb, Kb, Qn2, Kn2);
    sp_kernel<<<1, 256, 0, stream>>>(Gb, out + (size_t)NB * NL * ND);
    scan_kernel<<<NB, 512, 0, stream>>>(init_mem, masks, Qb, Kb, Vb, Gb, Qn2, Kn2, out);
}

// Round 6
// 6076.359 us; speedup vs baseline: 1.1316x; 1.1316x over previous
//
#include <hip/hip_runtime.h>
#include <math.h>

#define NB 8
#define NL 512
#define NS 128
#define ND 256

constexpr float SHARPNESS = 2.0f;
constexpr float WTGT = 1.0f / 2000.0f;
constexpr float EPS = 1e-12f;

// ---------------------------------------------------------------------------
// Projection kernel: Q = h Wq^T + bq, K, V, gate = sigmoid(h Wg^T + bg)
// grid = (NB*NL)/16 blocks, 256 threads. Each block: 16 (b,l) rows, thread = d.
// ---------------------------------------------------------------------------
__global__ __launch_bounds__(256) void proj_kernel(
    const float* __restrict__ hseq,
    const float* __restrict__ Wq, const float* __restrict__ bq,
    const float* __restrict__ Wk, const float* __restrict__ bk,
    const float* __restrict__ Wv, const float* __restrict__ bv,
    const float* __restrict__ Wg, const float* __restrict__ bg,
    float* __restrict__ Qo, float* __restrict__ Ko,
    float* __restrict__ Vo, float* __restrict__ Go)
{
    __shared__ float hs[16][ND + 4];
    const int tid = threadIdx.x;
    const int bl0 = blockIdx.x * 16;

    for (int k = 0; k < 16; ++k)
        hs[k][tid] = hseq[(size_t)(bl0 + k) * ND + tid];
    __syncthreads();

    const int d = tid;
    for (int mat = 0; mat < 3; ++mat) {
        const float* W    = (mat == 0) ? Wq : (mat == 1) ? Wk : Wv;
        const float* bias = (mat == 0) ? bq : (mat == 1) ? bk : bv;
        float* O          = (mat == 0) ? Qo : (mat == 1) ? Ko : Vo;
        float acc[16];
        const float b0 = bias[d];
        #pragma unroll
        for (int i = 0; i < 16; ++i) acc[i] = b0;
        const float4* Wrow = (const float4*)(W + (size_t)d * ND);
        for (int j4 = 0; j4 < 64; ++j4) {
            const float4 w4 = Wrow[j4];
            #pragma unroll
            for (int i = 0; i < 16; ++i) {
                const float4 h4 = *(const float4*)&hs[i][j4 * 4];
                acc[i] = fmaf(w4.x, h4.x,
                         fmaf(w4.y, h4.y,
                         fmaf(w4.z, h4.z,
                         fmaf(w4.w, h4.w, acc[i]))));
            }
        }
        #pragma unroll
        for (int i = 0; i < 16; ++i)
            O[(size_t)(bl0 + i) * ND + d] = acc[i];
    }

    {
        const int i = tid >> 4, j0 = (tid & 15) * 16;
        float p = 0.f;
        #pragma unroll
        for (int j = 0; j < 16; ++j)
            p = fmaf(Wg[j0 + j], hs[i][j0 + j], p);
        #pragma unroll
        for (int m = 1; m < 16; m <<= 1) p += __shfl_xor(p, m);
        if ((tid & 15) == 0) {
            const float z = p + bg[0];
            Go[bl0 + i] = 1.f / (1.f + __expf(-z));
        }
    }
}

// ---------------------------------------------------------------------------
// Per-(b,l) INVERTED norms: 1/max(||.||, eps). grid = NB*NL blocks, 1 wave.
// ---------------------------------------------------------------------------
__global__ __launch_bounds__(64) void norm_kernel(
    const float* __restrict__ Qb, const float* __restrict__ Kb,
    float* __restrict__ Qni, float* __restrict__ Kni)
{
    const int bl = blockIdx.x;
    const int lane = threadIdx.x;
    const float4 q4 = ((const float4*)(Qb + (size_t)bl * ND))[lane];
    const float4 k4 = ((const float4*)(Kb + (size_t)bl * ND))[lane];
    float qq = q4.x*q4.x + q4.y*q4.y + q4.z*q4.z + q4.w*q4.w;
    float kk = k4.x*k4.x + k4.y*k4.y + k4.z*k4.z + k4.w*k4.w;
    #pragma unroll
    for (int m = 1; m < 64; m <<= 1) { qq += __shfl_xor(qq, m); kk += __shfl_xor(kk, m); }
    if (lane == 0) {
        Qni[bl] = 1.f / fmaxf(sqrtf(qq), EPS);
        Kni[bl] = 1.f / fmaxf(sqrtf(kk), EPS);
    }
}

// ---------------------------------------------------------------------------
// sp = mean_l (mean_b gate - WTGT)^2. 1 block, 256 threads.
// ---------------------------------------------------------------------------
__global__ __launch_bounds__(256) void sp_kernel(
    const float* __restrict__ Go, float* __restrict__ out_sp)
{
    const int tid = threadIdx.x;
    float s = 0.f;
    for (int l = tid; l < NL; l += 256) {
        float gsum = 0.f;
        #pragma unroll
        for (int b = 0; b < NB; ++b) gsum += Go[b * NL + l];
        const float d = gsum * (1.f / NB) - WTGT;
        s += d * d;
    }
    #pragma unroll
    for (int m = 1; m < 64; m <<= 1) s += __shfl_xor(s, m);
    __shared__ float ws[4];
    if ((tid & 63) == 0) ws[tid >> 6] = s;
    __syncthreads();
    if (tid == 0) out_sp[0] = (ws[0] + ws[1] + ws[2] + ws[3]) * (1.f / NL);
}

// ---------------------------------------------------------------------------
// Sequential scan. grid = NB blocks, 512 threads (8 waves).
// Thread t: row r = t>>2 (0..127), chunk c = t&3, owns mem[r][c*64 .. c*64+63]
// in registers (64 VGPRs). __shfl_xor only (round-1-proven lowering).
// Softmax-max dropped (logits in [-2,2]). 2 barriers/step.
// ---------------------------------------------------------------------------
__global__ __launch_bounds__(512, 1) void scan_kernel(
    const float* __restrict__ init_mem, const float* __restrict__ masks,
    const float* __restrict__ Qb, const float* __restrict__ Kb,
    const float* __restrict__ Vb, const float* __restrict__ Gb,
    const float* __restrict__ Qni, const float* __restrict__ Kni,
    float* __restrict__ out)
{
    const int b    = blockIdx.x;
    const int t    = (int)threadIdx.x;
    const int lane = t & 63;
    const int w    = t >> 6;
    const int r    = t >> 2;
    const int c    = t & 3;
    const int d0   = c * 64;

    __shared__ float2 redsum[8];
    __shared__ float  rvpart[8][ND];

    float mem[64];
    {
        const float4* p4 = (const float4*)(init_mem + ((size_t)b * NS + r) * ND + d0);
        #pragma unroll
        for (int j = 0; j < 16; ++j) {
            const float4 v = p4[j];
            mem[4*j+0] = v.x; mem[4*j+1] = v.y; mem[4*j+2] = v.z; mem[4*j+3] = v.w;
        }
    }

    const bool h1 = (lane & 4)  != 0;
    const bool h2 = (lane & 8)  != 0;
    const bool h3 = (lane & 16) != 0;
    const bool h4 = (lane & 32) != 0;
    const int off = (h1 ? 32 : 0) + (h2 ? 16 : 0) + (h3 ? 8 : 0) + (h4 ? 4 : 0);

    #pragma unroll 1
    for (int step = 0; step < NL; ++step) {
        const size_t blt = (size_t)b * NL + step;
        const float qni  = Qni[blt];
        const float kni  = Kni[blt];
        const float g_   = Gb[blt];
        const float mval = masks[blt];

        // ---- pass 1: fused dots + row norm; q,k streamed from L2/L3 at use ----
        float dq = 0.f, dk = 0.f, nn = 0.f;
        {
            const float4* qp = (const float4*)(Qb + blt * ND + d0);
            const float4* kp = (const float4*)(Kb + blt * ND + d0);
            #pragma unroll
            for (int j = 0; j < 16; ++j) {
                const float4 q4 = qp[j];
                const float4 k4 = kp[j];
                const float m0 = mem[4*j+0], m1 = mem[4*j+1];
                const float m2 = mem[4*j+2], m3 = mem[4*j+3];
                dq = fmaf(m0, q4.x, fmaf(m1, q4.y, fmaf(m2, q4.z, fmaf(m3, q4.w, dq))));
                dk = fmaf(m0, k4.x, fmaf(m1, k4.y, fmaf(m2, k4.z, fmaf(m3, k4.w, dk))));
                nn = fmaf(m0, m0, fmaf(m1, m1, fmaf(m2, m2, fmaf(m3, m3, nn))));
            }
        }

        // prefetch V row into registers: latency hides under the softmax window
        float v4r[64];
        {
            const float4* vp = (const float4*)(Vb + blt * ND + d0);
            #pragma unroll
            for (int j = 0; j < 16; ++j) {
                const float4 v4 = vp[j];
                v4r[4*j+0] = v4.x; v4r[4*j+1] = v4.y;
                v4r[4*j+2] = v4.z; v4r[4*j+3] = v4.w;
            }
        }

        // combine the 4 chunk partials of this row (quad lanes)
        dq += __shfl_xor(dq, 1); dq += __shfl_xor(dq, 2);
        dk += __shfl_xor(dk, 1); dk += __shfl_xor(dk, 2);
        nn += __shfl_xor(nn, 1); nn += __shfl_xor(nn, 2);

        const float rinv = 1.f / fmaxf(sqrtf(nn), EPS);
        const float sim  = dq * rinv * qni * SHARPNESS;   // in [-2, 2]
        const float wsim = dk * rinv * kni * SHARPNESS;   // in [-2, 2]
        const float e1 = __expf(sim);
        const float e2 = __expf(wsim);

        // ---- softmax denominators (no max phase). Rows duplicated x4. ----
        float s1 = e1, s2 = e2;
        #pragma unroll
        for (int m_ = 1; m_ < 64; m_ <<= 1) {
            s1 += __shfl_xor(s1, m_);
            s2 += __shfl_xor(s2, m_);
        }
        if (lane == 0) redsum[w] = make_float2(s1, s2);
        __syncthreads();
        float S1 = 0.f, S2 = 0.f;
        #pragma unroll
        for (int i = 0; i < 8; ++i) { const float2 sv = redsum[i]; S1 += sv.x; S2 += sv.y; }

        const float rw = e1 * (4.f / S1);              // x4 dup compensated
        const float a  = g_ * (e2 * (4.f / S2));       // write coefficient

        // ---- read_v: reduce-scatter over the 16 lanes {c, c+4, ..., c+60} ----
        float red[32];
        #pragma unroll
        for (int k2 = 0; k2 < 32; ++k2) {
            const float plo = rw * mem[k2];
            const float phi = rw * mem[32 + k2];
            red[k2] = (h1 ? phi : plo) + __shfl_xor(h1 ? plo : phi, 4);
        }
        #pragma unroll
        for (int k2 = 0; k2 < 16; ++k2)
            red[k2] = (h2 ? red[16+k2] : red[k2]) + __shfl_xor(h2 ? red[k2] : red[16+k2], 8);
        #pragma unroll
        for (int k2 = 0; k2 < 8; ++k2)
            red[k2] = (h3 ? red[8+k2] : red[k2]) + __shfl_xor(h3 ? red[k2] : red[8+k2], 16);
        #pragma unroll
        for (int k2 = 0; k2 < 4; ++k2)
            red[k2] = (h4 ? red[4+k2] : red[k2]) + __shfl_xor(h4 ? red[k2] : red[4+k2], 32);
        *(float4*)&rvpart[w][d0 + off] = make_float4(red[0], red[1], red[2], red[3]);

        // ---- update mem: mem += a*(v - mem), v already in registers ----
        #pragma unroll
        for (int j = 0; j < 64; ++j)
            mem[j] = fmaf(a, v4r[j] - mem[j], mem[j]);
        if (mval != 1.0f) {
            #pragma unroll
            for (int j = 0; j < 64; ++j) mem[j] *= mval;
        }

        __syncthreads();
        if (t < ND) {
            float s = 0.f;
            #pragma unroll
            for (int ww = 0; ww < 8; ++ww) s += rvpart[ww][t];
            out[blt * ND + t] = s;
        }
        // next step's redsum/rvpart writes are behind the next barrier: safe.
    }
}

// ---------------------------------------------------------------------------
extern "C" void kernel_launch(void* const* d_in, const int* in_sizes, int n_in,
                              void* d_out, int out_size, void* d_ws, size_t ws_size,
                              hipStream_t stream)
{
    (void)in_sizes; (void)n_in; (void)out_size; (void)ws_size;

    const float* init_mem = (const float*)d_in[0];
    const float* hseq     = (const float*)d_in[1];
    const float* masks    = (const float*)d_in[2];
    const float* Wq = (const float*)d_in[3];  const float* bq = (const float*)d_in[4];
    const float* Wk = (const float*)d_in[5];  const float* bk = (const float*)d_in[6];
    const float* Wv = (const float*)d_in[7];  const float* bv = (const float*)d_in[8];
    const float* Wg = (const float*)d_in[9];  const float* bg = (const float*)d_in[10];
    float* out = (float*)d_out;

    float* ws  = (float*)d_ws;
    float* Qb  = ws;                                   // NB*NL*ND
    float* Kb  = Qb + (size_t)NB * NL * ND;            // NB*NL*ND
    float* Vb  = Kb + (size_t)NB * NL * ND;            // NB*NL*ND
    float* Gb  = Vb + (size_t)NB * NL * ND;            // NB*NL
    float* Qni = Gb + NB * NL;                         // NB*NL
    float* Kni = Qni + NB * NL;                        // NB*NL

    proj_kernel<<<(NB * NL) / 16, 256, 0, stream>>>(hseq, Wq, bq, Wk, bk, Wv, bv,
                                                    Wg, bg, Qb, Kb, Vb, Gb);
    norm_kernel<<<NB * NL, 64, 0, stream>>>(Qb, Kb, Qni, Kni);
    sp_kernel<<<1, 256, 0, stream>>>(Gb, out + (size_t)NB * NL * ND);
    scan_kernel<<<NB, 512, 0, stream>>>(init_mem, masks, Qb, Kb, Vb, Gb, Qni, Kni, out);
}